// Round 1
// baseline (398.202 us; speedup 1.0000x reference)
//
#include <hip/hip_runtime.h>

#define N 8192
#define D 128
// TEMPERATURE = 0.5 -> exp(x/T) = exp2(x * 2*log2(e))
#define EXP_SCALE 2.8853900817779268f

typedef __bf16 bf16;
typedef __bf16 bf16x8 __attribute__((ext_vector_type(8)));
typedef float f32x4 __attribute__((ext_vector_type(4)));

// workspace layout
#define ZBF_OFF 0                    // N*D bf16 = 2 MB
#define DEN_OFF (N * D * 2)          // N fp32 = 32 KB
#define S_OFF   (DEN_OFF + N * 4)    // 128 fp32
#define SP_OFF  (S_OFF + 512)        // 128 fp32

// ---------------------------------------------------------------------------
// Kernel 1: row-normalize. Writes bf16 z_n (eps=1e-8) for the sim matrix,
// accumulates column sums of z (eps=1e-12, nodes) and z_p (pair_nodes).
// 64 threads (1 wave) per block, 16 rows per block.
// blocks [0,512) -> nodes, [512,1024) -> pair_nodes.
// ---------------------------------------------------------------------------
__global__ __launch_bounds__(64) void norm_kernel(
    const float* __restrict__ nodes, const float* __restrict__ pair,
    bf16* __restrict__ zbf, float* __restrict__ svec, float* __restrict__ spvec)
{
    const int lane = threadIdx.x;
    const bool isPair = blockIdx.x >= 512;
    const float* src = isPair ? pair : nodes;
    const int row0 = (blockIdx.x & 511) * 16;

    float acc0 = 0.f, acc1 = 0.f;
    for (int rr = 0; rr < 16; ++rr) {
        const int row = row0 + rr;
        const float x0 = src[row * D + lane];
        const float x1 = src[row * D + lane + 64];
        float ss = x0 * x0 + x1 * x1;
        #pragma unroll
        for (int m = 32; m >= 1; m >>= 1) ss += __shfl_xor(ss, m, 64);
        const float nrm = sqrtf(ss);
        const float inv12 = 1.f / fmaxf(nrm, 1e-12f);
        acc0 += x0 * inv12;
        acc1 += x1 * inv12;
        if (!isPair) {
            const float inv8 = 1.f / fmaxf(nrm, 1e-8f);
            zbf[row * D + lane]      = (bf16)(x0 * inv8);
            zbf[row * D + lane + 64] = (bf16)(x1 * inv8);
        }
    }
    float* dst = isPair ? spvec : svec;
    atomicAdd(&dst[lane], acc0);
    atomicAdd(&dst[lane + 64], acc1);
}

// ---------------------------------------------------------------------------
// Kernel 2: fused SYRK + exp + rowsum.
// Tile 128x128, 256 threads = 4 waves (2x2 of 64x64 each),
// mfma_f32_16x16x32_bf16, K=128 staged as 2 x BK=64 in LDS.
// Row pad to 80 bf16 (160 B): bank(m,q) = (8m+4q)%32 spreads uniformly
// (8 lanes per 4-bank slot = ds_read_b128 floor).
// Epilogue: e = exp2(sim*SC), diagonal masked exactly, shuffle rowsum over
// the 16 column-lanes, atomicAdd partial row sums to den[].
// ---------------------------------------------------------------------------
#define LDP 80

__global__ __launch_bounds__(256) void gemm_kernel(
    const bf16* __restrict__ zbf, float* __restrict__ den)
{
    __shared__ bf16 As[128 * LDP];
    __shared__ bf16 Bs[128 * LDP];

    const int tid  = threadIdx.x;
    const int lane = tid & 63, wave = tid >> 6;
    const int wm = wave >> 1, wn = wave & 1;
    const int quad = lane >> 4, c = lane & 15;
    const int jbase = blockIdx.y * 128;
    const int kbase = blockIdx.x * 128;

    f32x4 acc[4][4];
    #pragma unroll
    for (int i = 0; i < 4; ++i)
        #pragma unroll
        for (int j = 0; j < 4; ++j) acc[i][j] = (f32x4){0.f, 0.f, 0.f, 0.f};

    #pragma unroll
    for (int kh = 0; kh < 2; ++kh) {
        __syncthreads();  // previous iter's LDS reads done before overwrite
        #pragma unroll
        for (int i = 0; i < 4; ++i) {
            const int chunk = tid + 256 * i;       // 0..1023
            const int row = chunk >> 3;            // 0..127
            const int c8  = (chunk & 7) * 8;       // col offset in bf16
            const uint4 va = *(const uint4*)(zbf + (jbase + row) * D + kh * 64 + c8);
            const uint4 vb = *(const uint4*)(zbf + (kbase + row) * D + kh * 64 + c8);
            *(uint4*)(&As[row * LDP + c8]) = va;
            *(uint4*)(&Bs[row * LDP + c8]) = vb;
        }
        __syncthreads();
        #pragma unroll
        for (int ks = 0; ks < 2; ++ks) {
            const int kk = ks * 32;
            bf16x8 af[4], bfr[4];
            #pragma unroll
            for (int mi = 0; mi < 4; ++mi)
                af[mi] = *(const bf16x8*)(&As[(wm * 64 + mi * 16 + c) * LDP + kk + quad * 8]);
            #pragma unroll
            for (int ni = 0; ni < 4; ++ni)
                bfr[ni] = *(const bf16x8*)(&Bs[(wn * 64 + ni * 16 + c) * LDP + kk + quad * 8]);
            #pragma unroll
            for (int mi = 0; mi < 4; ++mi)
                #pragma unroll
                for (int ni = 0; ni < 4; ++ni)
                    acc[mi][ni] = __builtin_amdgcn_mfma_f32_16x16x32_bf16(
                        af[mi], bfr[ni], acc[mi][ni], 0, 0, 0);
        }
    }

    // epilogue: exp + masked rowsum
    #pragma unroll
    for (int mi = 0; mi < 4; ++mi) {
        const int growb = jbase + wm * 64 + mi * 16 + quad * 4;
        float rs[4] = {0.f, 0.f, 0.f, 0.f};
        #pragma unroll
        for (int ni = 0; ni < 4; ++ni) {
            const int gcol = kbase + wn * 64 + ni * 16 + c;
            const f32x4 cv = acc[mi][ni];
            #pragma unroll
            for (int r = 0; r < 4; ++r) {
                float e = __builtin_exp2f(cv[r] * EXP_SCALE);
                if (growb + r == gcol) e = 0.f;  // exact self-mask
                rs[r] += e;
            }
        }
        #pragma unroll
        for (int r = 0; r < 4; ++r) {
            #pragma unroll
            for (int m = 1; m <= 8; m <<= 1) rs[r] += __shfl_xor(rs[r], m, 64);
        }
        if (c == 0) {
            #pragma unroll
            for (int r = 0; r < 4; ++r) atomicAdd(&den[growb + r], rs[r]);
        }
    }
}

// ---------------------------------------------------------------------------
// Kernel 3: loss = sum_j log(den[j]) - dot(s, sp)/(T*N)
// ---------------------------------------------------------------------------
__global__ __launch_bounds__(256) void final_kernel(
    const float* __restrict__ den, const float* __restrict__ s,
    const float* __restrict__ sp, float* __restrict__ out)
{
    __shared__ float red[4];
    const int tid = threadIdx.x;
    float v = 0.f;
    for (int j = tid; j < N; j += 256) v += logf(den[j]);
    if (tid < 128) v -= s[tid] * sp[tid] * (1.f / 4096.f);  // 1/(T*N)
    #pragma unroll
    for (int m = 32; m >= 1; m >>= 1) v += __shfl_xor(v, m, 64);
    if ((tid & 63) == 0) red[tid >> 6] = v;
    __syncthreads();
    if (tid == 0) out[0] = red[0] + red[1] + red[2] + red[3];
}

extern "C" void kernel_launch(void* const* d_in, const int* in_sizes, int n_in,
                              void* d_out, int out_size, void* d_ws, size_t ws_size,
                              hipStream_t stream)
{
    const float* nodes = (const float*)d_in[0];
    const float* pair  = (const float*)d_in[1];
    // d_in[2] (labels) and d_in[3] (mask = eye(N)) are unused: labels don't
    // enter the loss; the self-mask is applied exactly in-kernel.

    char*  ws  = (char*)d_ws;
    bf16*  zbf = (bf16*)(ws + ZBF_OFF);
    float* den = (float*)(ws + DEN_OFF);
    float* s   = (float*)(ws + S_OFF);
    float* sp  = (float*)(ws + SP_OFF);

    // zero den + s + sp (ws is poisoned 0xAA before every timed call)
    hipMemsetAsync(ws + DEN_OFF, 0, N * 4 + 1024, stream);

    hipLaunchKernelGGL(norm_kernel, dim3(1024), dim3(64), 0, stream,
                       nodes, pair, zbf, s, sp);
    hipLaunchKernelGGL(gemm_kernel, dim3(64, 64), dim3(256), 0, stream, zbf, den);
    hipLaunchKernelGGL(final_kernel, dim3(1), dim3(256), 0, stream,
                       den, s, sp, (float*)d_out);
}

// Round 2
// 352.805 us; speedup vs baseline: 1.1287x; 1.1287x over previous
//
#include <hip/hip_runtime.h>

#define N 8192
#define D 128
#define NT 64   // 128-row tiles per dimension
// TEMPERATURE = 0.5 -> exp(x/T) = exp2(x * 2*log2(e))
#define EXP_SCALE 2.8853900817779268f

typedef __bf16 bf16;
typedef __bf16 bf16x2 __attribute__((ext_vector_type(2)));
typedef __bf16 bf16x8 __attribute__((ext_vector_type(8)));
typedef float f32x4 __attribute__((ext_vector_type(4)));

// workspace layout
#define ZBF_OFF 0                    // N*D bf16 = 2 MB
#define DEN_OFF (N * D * 2)          // N fp32 = 32 KB
#define S_OFF   (DEN_OFF + N * 4)    // 128 fp32
#define SP_OFF  (S_OFF + 512)        // 128 fp32

// ---------------------------------------------------------------------------
// Kernel 1: row-normalize. Writes bf16 z_n (eps=1e-8) for the sim matrix,
// accumulates column sums of z (eps=1e-12) and z_p. 256 threads = 4 waves,
// 64 rows/block; float2 loads (lane l covers cols 2l, 2l+1); block-local
// LDS combine -> 1 coalesced atomicAdd set per block (8x fewer than R1).
// blocks [0,128) -> nodes, [128,256) -> pair_nodes.
// ---------------------------------------------------------------------------
__global__ __launch_bounds__(256) void norm_kernel(
    const float* __restrict__ nodes, const float* __restrict__ pair,
    bf16* __restrict__ zbf, float* __restrict__ svec, float* __restrict__ spvec)
{
    __shared__ float red[4][128];
    const int tid = threadIdx.x;
    const int lane = tid & 63, wave = tid >> 6;
    const bool isPair = blockIdx.x >= 128;
    const float* src = isPair ? pair : nodes;
    const int row0 = (blockIdx.x & 127) * 64 + wave * 16;

    float acc0 = 0.f, acc1 = 0.f;
    for (int rr = 0; rr < 16; ++rr) {
        const int row = row0 + rr;
        const float2 x = *(const float2*)(src + row * D + lane * 2);
        float ss = x.x * x.x + x.y * x.y;
        #pragma unroll
        for (int m = 32; m >= 1; m >>= 1) ss += __shfl_xor(ss, m, 64);
        const float nrm = sqrtf(ss);
        const float inv12 = 1.f / fmaxf(nrm, 1e-12f);
        acc0 += x.x * inv12;
        acc1 += x.y * inv12;
        if (!isPair) {
            const float inv8 = 1.f / fmaxf(nrm, 1e-8f);
            bf16x2 pk;
            pk[0] = (bf16)(x.x * inv8);
            pk[1] = (bf16)(x.y * inv8);
            *(bf16x2*)(zbf + row * D + lane * 2) = pk;
        }
    }
    red[wave][lane * 2]     = acc0;
    red[wave][lane * 2 + 1] = acc1;
    __syncthreads();
    if (tid < 128) {
        float* dst = isPair ? spvec : svec;
        atomicAdd(&dst[tid], red[0][tid] + red[1][tid] + red[2][tid] + red[3][tid]);
    }
}

// ---------------------------------------------------------------------------
// Kernel 2: fused symmetric SYRK + exp + row/col sums, upper triangle only.
// 2080 blocks = NT*(NT+1)/2 tile pairs (ti <= tj). Tile 128x128, 4 waves
// (2x2 of 64x64), mfma_f32_16x16x32_bf16, K=128 staged 2 x BK=64, LDS row
// pad to 80 bf16 (conflict-free b128). Epilogue: e = exp2(sim*SC), exact
// diag mask; per-lane partials -> shuffle -> LDS rowacc/colacc -> one
// coalesced global atomic pass. Off-diag tiles feed den twice (row+col,
// by symmetry); diag tiles feed rows only.
// ---------------------------------------------------------------------------
#define LDP 80

__global__ __launch_bounds__(256) void gemm_kernel(
    const bf16* __restrict__ zbf, float* __restrict__ den)
{
    __shared__ bf16 As[128 * LDP];
    __shared__ bf16 Bs[128 * LDP];
    __shared__ float rowacc[128];
    __shared__ float colacc[128];

    // decode upper-tri pair: offset(ti) = ti*(2*NT+1-ti)/2
    int b = blockIdx.x;
    int ti = (int)((2.0 * NT + 1.0 - sqrt((2.0 * NT + 1.0) * (2.0 * NT + 1.0) - 8.0 * (double)b)) * 0.5);
    while (ti > 0 && ti * (2 * NT + 1 - ti) / 2 > b) --ti;
    while ((ti + 1) * (2 * NT - ti) / 2 <= b) ++ti;
    const int tj = ti + (b - ti * (2 * NT + 1 - ti) / 2);
    const bool diag = (ti == tj);

    const int tid  = threadIdx.x;
    const int lane = tid & 63, wave = tid >> 6;
    const int wm = wave >> 1, wn = wave & 1;
    const int quad = lane >> 4, c = lane & 15;
    const int ibase = ti * 128;   // rows of this tile (As)
    const int jbase = tj * 128;   // cols of this tile (Bs)

    if (tid < 128) { rowacc[tid] = 0.f; colacc[tid] = 0.f; }

    f32x4 acc[4][4];
    #pragma unroll
    for (int i = 0; i < 4; ++i)
        #pragma unroll
        for (int j = 0; j < 4; ++j) acc[i][j] = (f32x4){0.f, 0.f, 0.f, 0.f};

    #pragma unroll
    for (int kh = 0; kh < 2; ++kh) {
        __syncthreads();  // also covers rowacc/colacc init on kh==0
        #pragma unroll
        for (int i = 0; i < 4; ++i) {
            const int chunk = tid + 256 * i;       // 0..1023
            const int row = chunk >> 3;            // 0..127
            const int c8  = (chunk & 7) * 8;       // bf16 col offset
            const uint4 va = *(const uint4*)(zbf + (ibase + row) * D + kh * 64 + c8);
            const uint4 vb = *(const uint4*)(zbf + (jbase + row) * D + kh * 64 + c8);
            *(uint4*)(&As[row * LDP + c8]) = va;
            *(uint4*)(&Bs[row * LDP + c8]) = vb;
        }
        __syncthreads();
        #pragma unroll
        for (int ks = 0; ks < 2; ++ks) {
            const int kk = ks * 32;
            bf16x8 af[4], bfr[4];
            #pragma unroll
            for (int mi = 0; mi < 4; ++mi)
                af[mi] = *(const bf16x8*)(&As[(wm * 64 + mi * 16 + c) * LDP + kk + quad * 8]);
            #pragma unroll
            for (int ni = 0; ni < 4; ++ni)
                bfr[ni] = *(const bf16x8*)(&Bs[(wn * 64 + ni * 16 + c) * LDP + kk + quad * 8]);
            #pragma unroll
            for (int mi = 0; mi < 4; ++mi)
                #pragma unroll
                for (int ni = 0; ni < 4; ++ni)
                    acc[mi][ni] = __builtin_amdgcn_mfma_f32_16x16x32_bf16(
                        af[mi], bfr[ni], acc[mi][ni], 0, 0, 0);
        }
    }

    // ---- epilogue: exp + masked row/col partial sums -----------------------
    float rowp[4][4];   // [mi][r]: sum over this lane's 16 cols x 4 ni frags
    float colp[4];      // [ni]:    sum over this lane's 16 rows (quad) x 4 mi
    #pragma unroll
    for (int mi = 0; mi < 4; ++mi)
        #pragma unroll
        for (int r = 0; r < 4; ++r) rowp[mi][r] = 0.f;
    #pragma unroll
    for (int ni = 0; ni < 4; ++ni) colp[ni] = 0.f;

    #pragma unroll
    for (int mi = 0; mi < 4; ++mi) {
        const int lrow0 = wm * 64 + mi * 16 + quad * 4;
        #pragma unroll
        for (int ni = 0; ni < 4; ++ni) {
            const int lcol = wn * 64 + ni * 16 + c;
            const f32x4 cv = acc[mi][ni];
            #pragma unroll
            for (int r = 0; r < 4; ++r) {
                float e = __builtin_amdgcn_exp2f(cv[r] * EXP_SCALE);
                if (diag && (lrow0 + r == lcol)) e = 0.f;  // exact self-mask
                rowp[mi][r] += e;
                colp[ni]    += e;
            }
        }
    }

    // rowsum: reduce over the 16 column-lanes (bits 0..3)
    #pragma unroll
    for (int mi = 0; mi < 4; ++mi)
        #pragma unroll
        for (int r = 0; r < 4; ++r) {
            #pragma unroll
            for (int m = 1; m <= 8; m <<= 1)
                rowp[mi][r] += __shfl_xor(rowp[mi][r], m, 64);
        }
    if (c == 0) {
        #pragma unroll
        for (int mi = 0; mi < 4; ++mi)
            #pragma unroll
            for (int r = 0; r < 4; ++r)
                atomicAdd(&rowacc[wm * 64 + mi * 16 + quad * 4 + r], rowp[mi][r]);
    }

    if (!diag) {
        // colsum: reduce over the 4 quads (bits 4..5)
        #pragma unroll
        for (int ni = 0; ni < 4; ++ni) {
            colp[ni] += __shfl_xor(colp[ni], 16, 64);
            colp[ni] += __shfl_xor(colp[ni], 32, 64);
        }
        if (quad == 0) {
            #pragma unroll
            for (int ni = 0; ni < 4; ++ni)
                atomicAdd(&colacc[wn * 64 + ni * 16 + c], colp[ni]);
        }
    }

    __syncthreads();
    if (tid < 128) {
        atomicAdd(&den[ibase + tid], rowacc[tid]);
        if (!diag) atomicAdd(&den[jbase + tid], colacc[tid]);
    }
}

// ---------------------------------------------------------------------------
// Kernel 3: loss = sum_j log(den[j]) - dot(s, sp)/(T*N)
// ---------------------------------------------------------------------------
__global__ __launch_bounds__(256) void final_kernel(
    const float* __restrict__ den, const float* __restrict__ s,
    const float* __restrict__ sp, float* __restrict__ out)
{
    __shared__ float red[4];
    const int tid = threadIdx.x;
    float v = 0.f;
    for (int j = tid; j < N; j += 256) v += logf(den[j]);
    if (tid < 128) v -= s[tid] * sp[tid] * (1.f / 4096.f);  // 1/(T*N)
    #pragma unroll
    for (int m = 32; m >= 1; m >>= 1) v += __shfl_xor(v, m, 64);
    if ((tid & 63) == 0) red[tid >> 6] = v;
    __syncthreads();
    if (tid == 0) out[0] = red[0] + red[1] + red[2] + red[3];
}

extern "C" void kernel_launch(void* const* d_in, const int* in_sizes, int n_in,
                              void* d_out, int out_size, void* d_ws, size_t ws_size,
                              hipStream_t stream)
{
    const float* nodes = (const float*)d_in[0];
    const float* pair  = (const float*)d_in[1];
    // d_in[2] (labels) and d_in[3] (mask = eye(N)) are unused: labels don't
    // enter the loss; the self-mask is applied exactly in-kernel.

    char*  ws  = (char*)d_ws;
    bf16*  zbf = (bf16*)(ws + ZBF_OFF);
    float* den = (float*)(ws + DEN_OFF);
    float* s   = (float*)(ws + S_OFF);
    float* sp  = (float*)(ws + SP_OFF);

    // zero den + s + sp (ws is poisoned 0xAA before every timed call)
    hipMemsetAsync(ws + DEN_OFF, 0, N * 4 + 1024, stream);

    hipLaunchKernelGGL(norm_kernel, dim3(256), dim3(256), 0, stream,
                       nodes, pair, zbf, s, sp);
    hipLaunchKernelGGL(gemm_kernel, dim3(NT * (NT + 1) / 2), dim3(256), 0, stream,
                       zbf, den);
    hipLaunchKernelGGL(final_kernel, dim3(1), dim3(256), 0, stream,
                       den, s, sp, (float*)d_out);
}